// Round 1
// baseline (339.749 us; speedup 1.0000x reference)
//
#include <hip/hip_runtime.h>
#include <math.h>

#define NT    16384   // tokens = 4*64*64
#define CIN   96
#define DI    192
#define NS    16
#define SEQ   64
#define NSEQ  256     // sequences per direction (B*H == B*W)

__device__ __forceinline__ float silu_f(float v) {
    return v * (1.0f / (1.0f + __expf(-v)));
}

__device__ __forceinline__ float softplus_f(float v) {
    // logaddexp(v, 0) = max(v,0) + log1p(exp(-|v|))
    return fmaxf(v, 0.0f) + log1pf(__expf(-fabsf(v)));
}

// ---------------- K1: projection GEMM + activations + split ----------------
__global__ __launch_bounds__(256) void k1_proj(
    const float* __restrict__ x, const float* __restrict__ Win,
    const float* __restrict__ wconv,
    float* __restrict__ xc, float* __restrict__ sz,
    float* __restrict__ Bc, float* __restrict__ Cc, float* __restrict__ dt)
{
    __shared__ float xs[64 * 97];
    const int t0 = blockIdx.x * 64;
    for (int idx = threadIdx.x; idx < 64 * 96; idx += 256) {
        const int tt = idx / 96, k = idx - tt * 96;
        xs[tt * 97 + k] = x[(t0 + tt) * 96 + k];
    }
    __syncthreads();
    const int lane = threadIdx.x & 63;
    const int wv = __builtin_amdgcn_readfirstlane(threadIdx.x >> 6);
    const int t = t0 + lane;

    for (int g = 0; g < 19; ++g) {
        const int c0 = (wv * 19 + g) * 8;
        float acc[8] = {0.f,0.f,0.f,0.f,0.f,0.f,0.f,0.f};
        for (int k = 0; k < 96; k += 4) {
            const float x0 = xs[lane * 97 + k + 0];
            const float x1 = xs[lane * 97 + k + 1];
            const float x2 = xs[lane * 97 + k + 2];
            const float x3 = xs[lane * 97 + k + 3];
            #pragma unroll
            for (int j = 0; j < 8; ++j) {
                const float4 w4 = *reinterpret_cast<const float4*>(&Win[(c0 + j) * 96 + k]);
                acc[j] = fmaf(x0, w4.x, acc[j]);
                acc[j] = fmaf(x1, w4.y, acc[j]);
                acc[j] = fmaf(x2, w4.z, acc[j]);
                acc[j] = fmaf(x3, w4.w, acc[j]);
            }
        }
        if (c0 < DI) {
            #pragma unroll
            for (int j = 0; j < 8; ++j)
                acc[j] = silu_f(acc[j] * wconv[(c0 + j) * 3 + 1]);
            *reinterpret_cast<float4*>(&xc[t * DI + c0 + 0]) = *reinterpret_cast<float4*>(&acc[0]);
            *reinterpret_cast<float4*>(&xc[t * DI + c0 + 4]) = *reinterpret_cast<float4*>(&acc[4]);
        } else if (c0 < 2 * DI) {
            const int c = c0 - DI;
            #pragma unroll
            for (int j = 0; j < 8; ++j) acc[j] = silu_f(acc[j]);
            *reinterpret_cast<float4*>(&sz[t * DI + c + 0]) = *reinterpret_cast<float4*>(&acc[0]);
            *reinterpret_cast<float4*>(&sz[t * DI + c + 4]) = *reinterpret_cast<float4*>(&acc[4]);
        } else if (c0 < 2 * DI + NS) {
            const int c = c0 - 2 * DI;
            *reinterpret_cast<float4*>(&Bc[t * NS + c + 0]) = *reinterpret_cast<float4*>(&acc[0]);
            *reinterpret_cast<float4*>(&Bc[t * NS + c + 4]) = *reinterpret_cast<float4*>(&acc[4]);
        } else if (c0 < 2 * DI + 2 * NS) {
            const int c = c0 - (2 * DI + NS);
            *reinterpret_cast<float4*>(&Cc[t * NS + c + 0]) = *reinterpret_cast<float4*>(&acc[0]);
            *reinterpret_cast<float4*>(&Cc[t * NS + c + 4]) = *reinterpret_cast<float4*>(&acc[4]);
        } else {
            const int c = c0 - (2 * DI + 2 * NS);
            #pragma unroll
            for (int j = 0; j < 8; ++j) acc[j] = softplus_f(acc[j]);
            *reinterpret_cast<float4*>(&dt[t * DI + c + 0]) = *reinterpret_cast<float4*>(&acc[0]);
            *reinterpret_cast<float4*>(&dt[t * DI + c + 4]) = *reinterpret_cast<float4*>(&acc[4]);
        }
    }
}

// ---------------- K2: selective scans (horizontal + vertical) ----------------
__global__ __launch_bounds__(192) void k2_scan(
    const float* __restrict__ xc, const float* __restrict__ dt,
    const float* __restrict__ Bc, const float* __restrict__ Cc,
    const float* __restrict__ Alog, const float* __restrict__ Dvec,
    float* __restrict__ yh, float* __restrict__ yv)
{
    const int d = threadIdx.x;
    const int sid = blockIdx.x;
    const bool vert = sid >= NSEQ;
    const int s0 = vert ? (sid - NSEQ) : sid;

    float a[NS], h[NS];
    #pragma unroll
    for (int n = 0; n < NS; ++n) {
        a[n] = -__expf(Alog[d * NS + n]);
        h[n] = 0.f;
    }
    const float dD = Dvec[d];
    float* __restrict__ yout = vert ? yv : yh;

    // token index for step s
    const int base = vert ? (((s0 >> 6) << 12) + (s0 & 63)) : (s0 * 64);
    const int stride = vert ? 64 : 1;

    int t = base;
    float dtv = dt[t * DI + d];
    float xv  = xc[t * DI + d];
    float Bn[NS], Cn[NS];
    *reinterpret_cast<float4*>(&Bn[0])  = *reinterpret_cast<const float4*>(&Bc[t * NS + 0]);
    *reinterpret_cast<float4*>(&Bn[4])  = *reinterpret_cast<const float4*>(&Bc[t * NS + 4]);
    *reinterpret_cast<float4*>(&Bn[8])  = *reinterpret_cast<const float4*>(&Bc[t * NS + 8]);
    *reinterpret_cast<float4*>(&Bn[12]) = *reinterpret_cast<const float4*>(&Bc[t * NS + 12]);
    *reinterpret_cast<float4*>(&Cn[0])  = *reinterpret_cast<const float4*>(&Cc[t * NS + 0]);
    *reinterpret_cast<float4*>(&Cn[4])  = *reinterpret_cast<const float4*>(&Cc[t * NS + 4]);
    *reinterpret_cast<float4*>(&Cn[8])  = *reinterpret_cast<const float4*>(&Cc[t * NS + 8]);
    *reinterpret_cast<float4*>(&Cn[12]) = *reinterpret_cast<const float4*>(&Cc[t * NS + 12]);

    #pragma unroll 2
    for (int s = 0; s < SEQ; ++s) {
        // prefetch next step (clamped on last iteration)
        const int tn = (s + 1 < SEQ) ? (t + stride) : t;
        const float dtv_n = dt[tn * DI + d];
        const float xv_n  = xc[tn * DI + d];
        float Bn2[NS], Cn2[NS];
        *reinterpret_cast<float4*>(&Bn2[0])  = *reinterpret_cast<const float4*>(&Bc[tn * NS + 0]);
        *reinterpret_cast<float4*>(&Bn2[4])  = *reinterpret_cast<const float4*>(&Bc[tn * NS + 4]);
        *reinterpret_cast<float4*>(&Bn2[8])  = *reinterpret_cast<const float4*>(&Bc[tn * NS + 8]);
        *reinterpret_cast<float4*>(&Bn2[12]) = *reinterpret_cast<const float4*>(&Bc[tn * NS + 12]);
        *reinterpret_cast<float4*>(&Cn2[0])  = *reinterpret_cast<const float4*>(&Cc[tn * NS + 0]);
        *reinterpret_cast<float4*>(&Cn2[4])  = *reinterpret_cast<const float4*>(&Cc[tn * NS + 4]);
        *reinterpret_cast<float4*>(&Cn2[8])  = *reinterpret_cast<const float4*>(&Cc[tn * NS + 8]);
        *reinterpret_cast<float4*>(&Cn2[12]) = *reinterpret_cast<const float4*>(&Cc[tn * NS + 12]);

        const float dtx = dtv * xv;
        float y = 0.f;
        #pragma unroll
        for (int n = 0; n < NS; ++n) {
            const float dA = __expf(dtv * a[n]);
            h[n] = fmaf(dA, h[n], Bn[n] * dtx);
            y = fmaf(h[n], Cn[n], y);
        }
        yout[t * DI + d] = fmaf(xv, dD, y);

        t = tn; dtv = dtv_n; xv = xv_n;
        #pragma unroll
        for (int n = 0; n < NS; ++n) { Bn[n] = Bn2[n]; Cn[n] = Cn2[n]; }
    }
}

// ---------------- K3: fuse GEMM (y_cat @ Wf^T) * silu(z) ----------------
__global__ __launch_bounds__(256) void k3_fuse(
    const float* __restrict__ yh, const float* __restrict__ yv,
    const float* __restrict__ Wf, const float* __restrict__ sz,
    float* __restrict__ f)
{
    __shared__ float ys[64 * 193];
    const int tile = blockIdx.x >> 1;
    const int half = blockIdx.x & 1;
    const int t0 = tile * 64;
    const int lane = threadIdx.x & 63;
    const int wv = __builtin_amdgcn_readfirstlane(threadIdx.x >> 6);
    const int t = t0 + lane;

    float acc[3][8];
    #pragma unroll
    for (int g = 0; g < 3; ++g)
        #pragma unroll
        for (int j = 0; j < 8; ++j) acc[g][j] = 0.f;

    // phase 1: yh contribution (k = 0..191)
    for (int idx = threadIdx.x; idx < 64 * DI; idx += 256) {
        const int tt = idx / DI, k = idx - tt * DI;
        ys[tt * 193 + k] = yh[(t0 + tt) * DI + k];
    }
    __syncthreads();
    #pragma unroll
    for (int g = 0; g < 3; ++g) {
        const int c0 = half * 96 + wv * 24 + g * 8;
        for (int k = 0; k < DI; k += 4) {
            const float x0 = ys[lane * 193 + k + 0];
            const float x1 = ys[lane * 193 + k + 1];
            const float x2 = ys[lane * 193 + k + 2];
            const float x3 = ys[lane * 193 + k + 3];
            #pragma unroll
            for (int j = 0; j < 8; ++j) {
                const float4 w4 = *reinterpret_cast<const float4*>(&Wf[(c0 + j) * 384 + k]);
                acc[g][j] = fmaf(x0, w4.x, acc[g][j]);
                acc[g][j] = fmaf(x1, w4.y, acc[g][j]);
                acc[g][j] = fmaf(x2, w4.z, acc[g][j]);
                acc[g][j] = fmaf(x3, w4.w, acc[g][j]);
            }
        }
    }
    __syncthreads();
    // phase 2: yv contribution (k = 192..383)
    for (int idx = threadIdx.x; idx < 64 * DI; idx += 256) {
        const int tt = idx / DI, k = idx - tt * DI;
        ys[tt * 193 + k] = yv[(t0 + tt) * DI + k];
    }
    __syncthreads();
    #pragma unroll
    for (int g = 0; g < 3; ++g) {
        const int c0 = half * 96 + wv * 24 + g * 8;
        for (int k = 0; k < DI; k += 4) {
            const float x0 = ys[lane * 193 + k + 0];
            const float x1 = ys[lane * 193 + k + 1];
            const float x2 = ys[lane * 193 + k + 2];
            const float x3 = ys[lane * 193 + k + 3];
            #pragma unroll
            for (int j = 0; j < 8; ++j) {
                const float4 w4 = *reinterpret_cast<const float4*>(&Wf[(c0 + j) * 384 + 192 + k]);
                acc[g][j] = fmaf(x0, w4.x, acc[g][j]);
                acc[g][j] = fmaf(x1, w4.y, acc[g][j]);
                acc[g][j] = fmaf(x2, w4.z, acc[g][j]);
                acc[g][j] = fmaf(x3, w4.w, acc[g][j]);
            }
        }
    }
    // epilogue: * silu(z), store
    #pragma unroll
    for (int g = 0; g < 3; ++g) {
        const int c0 = half * 96 + wv * 24 + g * 8;
        const float4 sa = *reinterpret_cast<const float4*>(&sz[t * DI + c0 + 0]);
        const float4 sb = *reinterpret_cast<const float4*>(&sz[t * DI + c0 + 4]);
        acc[g][0] *= sa.x; acc[g][1] *= sa.y; acc[g][2] *= sa.z; acc[g][3] *= sa.w;
        acc[g][4] *= sb.x; acc[g][5] *= sb.y; acc[g][6] *= sb.z; acc[g][7] *= sb.w;
        *reinterpret_cast<float4*>(&f[t * DI + c0 + 0]) = *reinterpret_cast<float4*>(&acc[g][0]);
        *reinterpret_cast<float4*>(&f[t * DI + c0 + 4]) = *reinterpret_cast<float4*>(&acc[g][4]);
    }
}

// ---------------- K4: output GEMM ----------------
__global__ __launch_bounds__(256) void k4_out(
    const float* __restrict__ f, const float* __restrict__ Wout,
    float* __restrict__ out)
{
    __shared__ float fs[64 * 193];
    const int t0 = blockIdx.x * 64;
    for (int idx = threadIdx.x; idx < 64 * DI; idx += 256) {
        const int tt = idx / DI, k = idx - tt * DI;
        fs[tt * 193 + k] = f[(t0 + tt) * DI + k];
    }
    __syncthreads();
    const int lane = threadIdx.x & 63;
    const int wv = __builtin_amdgcn_readfirstlane(threadIdx.x >> 6);
    const int t = t0 + lane;

    #pragma unroll
    for (int g = 0; g < 3; ++g) {
        const int c0 = wv * 24 + g * 8;
        float acc[8] = {0.f,0.f,0.f,0.f,0.f,0.f,0.f,0.f};
        for (int k = 0; k < DI; k += 4) {
            const float x0 = fs[lane * 193 + k + 0];
            const float x1 = fs[lane * 193 + k + 1];
            const float x2 = fs[lane * 193 + k + 2];
            const float x3 = fs[lane * 193 + k + 3];
            #pragma unroll
            for (int j = 0; j < 8; ++j) {
                const float4 w4 = *reinterpret_cast<const float4*>(&Wout[(c0 + j) * DI + k]);
                acc[j] = fmaf(x0, w4.x, acc[j]);
                acc[j] = fmaf(x1, w4.y, acc[j]);
                acc[j] = fmaf(x2, w4.z, acc[j]);
                acc[j] = fmaf(x3, w4.w, acc[j]);
            }
        }
        *reinterpret_cast<float4*>(&out[t * 96 + c0 + 0]) = *reinterpret_cast<float4*>(&acc[0]);
        *reinterpret_cast<float4*>(&out[t * 96 + c0 + 4]) = *reinterpret_cast<float4*>(&acc[4]);
    }
}

extern "C" void kernel_launch(void* const* d_in, const int* in_sizes, int n_in,
                              void* d_out, int out_size, void* d_ws, size_t ws_size,
                              hipStream_t stream)
{
    const float* x     = (const float*)d_in[0];
    const float* Win   = (const float*)d_in[1];
    const float* wconv = (const float*)d_in[2];
    const float* Wf    = (const float*)d_in[3];
    const float* Wout  = (const float*)d_in[4];
    const float* Alog  = (const float*)d_in[5];
    const float* Dvec  = (const float*)d_in[6];
    float* out = (float*)d_out;

    float* ws = (float*)d_ws;
    float* xc = ws;                          // NT*DI
    float* dt = xc + (size_t)NT * DI;        // NT*DI
    float* sz = dt + (size_t)NT * DI;        // NT*DI
    float* Bc = sz + (size_t)NT * DI;        // NT*NS
    float* Cc = Bc + (size_t)NT * NS;        // NT*NS
    float* yh = Cc + (size_t)NT * NS;        // NT*DI
    float* yv = yh + (size_t)NT * DI;        // NT*DI
    float* f  = yv + (size_t)NT * DI;        // NT*DI

    k1_proj<<<NT / 64, 256, 0, stream>>>(x, Win, wconv, xc, sz, Bc, Cc, dt);
    k2_scan<<<2 * NSEQ, 192, 0, stream>>>(xc, dt, Bc, Cc, Alog, Dvec, yh, yv);
    k3_fuse<<<(NT / 64) * 2, 256, 0, stream>>>(yh, yv, Wf, sz, f);
    k4_out<<<NT / 64, 256, 0, stream>>>(f, Wout, out);
}

// Round 2
// 168.976 us; speedup vs baseline: 2.0106x; 2.0106x over previous
//
#include <hip/hip_runtime.h>
#include <math.h>

#define NT    16384   // tokens = 4*64*64
#define CIN   96
#define DI    192
#define NS    16
#define SEQ   64
#define NSEQ  256     // sequences per direction (B*H == B*W)

__device__ __forceinline__ float silu_f(float v) {
    return v * (1.0f / (1.0f + __expf(-v)));
}

__device__ __forceinline__ float softplus_f(float v) {
    return fmaxf(v, 0.0f) + log1pf(__expf(-fabsf(v)));
}

// ---------------- K1: projection GEMM + activations + split ----------------
// grid (NT/64, 19): block = 64 tokens x 32 channels, wave = 64 tok x 8 ch.
__global__ __launch_bounds__(256) void k1_proj(
    const float* __restrict__ x, const float* __restrict__ Win,
    const float* __restrict__ wconv,
    float* __restrict__ xc, float* __restrict__ sz,
    float* __restrict__ Bc, float* __restrict__ Cc, float* __restrict__ dt)
{
    __shared__ float xs[64 * 97];
    const int t0 = blockIdx.x * 64;
    for (int idx = threadIdx.x; idx < 64 * 96; idx += 256) {
        const int tt = idx / 96, k = idx - tt * 96;
        xs[tt * 97 + k] = x[(t0 + tt) * 96 + k];
    }
    __syncthreads();
    const int lane = threadIdx.x & 63;
    const int wv = __builtin_amdgcn_readfirstlane(threadIdx.x >> 6);
    const int t = t0 + lane;
    const int c0 = blockIdx.y * 32 + wv * 8;

    float acc[8] = {0.f,0.f,0.f,0.f,0.f,0.f,0.f,0.f};
    for (int k = 0; k < 96; k += 4) {
        const float x0 = xs[lane * 97 + k + 0];
        const float x1 = xs[lane * 97 + k + 1];
        const float x2 = xs[lane * 97 + k + 2];
        const float x3 = xs[lane * 97 + k + 3];
        #pragma unroll
        for (int j = 0; j < 8; ++j) {
            const float4 w4 = *reinterpret_cast<const float4*>(&Win[(c0 + j) * 96 + k]);
            acc[j] = fmaf(x0, w4.x, acc[j]);
            acc[j] = fmaf(x1, w4.y, acc[j]);
            acc[j] = fmaf(x2, w4.z, acc[j]);
            acc[j] = fmaf(x3, w4.w, acc[j]);
        }
    }
    if (c0 < DI) {
        #pragma unroll
        for (int j = 0; j < 8; ++j)
            acc[j] = silu_f(acc[j] * wconv[(c0 + j) * 3 + 1]);
        *reinterpret_cast<float4*>(&xc[t * DI + c0 + 0]) = *reinterpret_cast<float4*>(&acc[0]);
        *reinterpret_cast<float4*>(&xc[t * DI + c0 + 4]) = *reinterpret_cast<float4*>(&acc[4]);
    } else if (c0 < 2 * DI) {
        const int c = c0 - DI;
        #pragma unroll
        for (int j = 0; j < 8; ++j) acc[j] = silu_f(acc[j]);
        *reinterpret_cast<float4*>(&sz[t * DI + c + 0]) = *reinterpret_cast<float4*>(&acc[0]);
        *reinterpret_cast<float4*>(&sz[t * DI + c + 4]) = *reinterpret_cast<float4*>(&acc[4]);
    } else if (c0 < 2 * DI + NS) {
        const int c = c0 - 2 * DI;
        *reinterpret_cast<float4*>(&Bc[t * NS + c + 0]) = *reinterpret_cast<float4*>(&acc[0]);
        *reinterpret_cast<float4*>(&Bc[t * NS + c + 4]) = *reinterpret_cast<float4*>(&acc[4]);
    } else if (c0 < 2 * DI + 2 * NS) {
        const int c = c0 - (2 * DI + NS);
        *reinterpret_cast<float4*>(&Cc[t * NS + c + 0]) = *reinterpret_cast<float4*>(&acc[0]);
        *reinterpret_cast<float4*>(&Cc[t * NS + c + 4]) = *reinterpret_cast<float4*>(&acc[4]);
    } else {
        const int c = c0 - (2 * DI + 2 * NS);
        #pragma unroll
        for (int j = 0; j < 8; ++j) acc[j] = softplus_f(acc[j]);
        *reinterpret_cast<float4*>(&dt[t * DI + c + 0]) = *reinterpret_cast<float4*>(&acc[0]);
        *reinterpret_cast<float4*>(&dt[t * DI + c + 4]) = *reinterpret_cast<float4*>(&acc[4]);
    }
}

// ---------------- K2: selective scans (horizontal + vertical) ----------------
__global__ __launch_bounds__(192) void k2_scan(
    const float* __restrict__ xc, const float* __restrict__ dt,
    const float* __restrict__ Bc, const float* __restrict__ Cc,
    const float* __restrict__ Alog, const float* __restrict__ Dvec,
    float* __restrict__ yh, float* __restrict__ yv)
{
    const int d = threadIdx.x;
    const int sid = blockIdx.x;
    const bool vert = sid >= NSEQ;
    const int s0 = vert ? (sid - NSEQ) : sid;

    float a[NS], h[NS];
    #pragma unroll
    for (int n = 0; n < NS; ++n) {
        a[n] = -__expf(Alog[d * NS + n]);
        h[n] = 0.f;
    }
    const float dD = Dvec[d];
    float* __restrict__ yout = vert ? yv : yh;

    const int base = vert ? (((s0 >> 6) << 12) + (s0 & 63)) : (s0 * 64);
    const int stride = vert ? 64 : 1;

    int t = base;
    float dtv = dt[t * DI + d];
    float xv  = xc[t * DI + d];
    float Bn[NS], Cn[NS];
    *reinterpret_cast<float4*>(&Bn[0])  = *reinterpret_cast<const float4*>(&Bc[t * NS + 0]);
    *reinterpret_cast<float4*>(&Bn[4])  = *reinterpret_cast<const float4*>(&Bc[t * NS + 4]);
    *reinterpret_cast<float4*>(&Bn[8])  = *reinterpret_cast<const float4*>(&Bc[t * NS + 8]);
    *reinterpret_cast<float4*>(&Bn[12]) = *reinterpret_cast<const float4*>(&Bc[t * NS + 12]);
    *reinterpret_cast<float4*>(&Cn[0])  = *reinterpret_cast<const float4*>(&Cc[t * NS + 0]);
    *reinterpret_cast<float4*>(&Cn[4])  = *reinterpret_cast<const float4*>(&Cc[t * NS + 4]);
    *reinterpret_cast<float4*>(&Cn[8])  = *reinterpret_cast<const float4*>(&Cc[t * NS + 8]);
    *reinterpret_cast<float4*>(&Cn[12]) = *reinterpret_cast<const float4*>(&Cc[t * NS + 12]);

    #pragma unroll 2
    for (int s = 0; s < SEQ; ++s) {
        const int tn = (s + 1 < SEQ) ? (t + stride) : t;
        const float dtv_n = dt[tn * DI + d];
        const float xv_n  = xc[tn * DI + d];
        float Bn2[NS], Cn2[NS];
        *reinterpret_cast<float4*>(&Bn2[0])  = *reinterpret_cast<const float4*>(&Bc[tn * NS + 0]);
        *reinterpret_cast<float4*>(&Bn2[4])  = *reinterpret_cast<const float4*>(&Bc[tn * NS + 4]);
        *reinterpret_cast<float4*>(&Bn2[8])  = *reinterpret_cast<const float4*>(&Bc[tn * NS + 8]);
        *reinterpret_cast<float4*>(&Bn2[12]) = *reinterpret_cast<const float4*>(&Bc[tn * NS + 12]);
        *reinterpret_cast<float4*>(&Cn2[0])  = *reinterpret_cast<const float4*>(&Cc[tn * NS + 0]);
        *reinterpret_cast<float4*>(&Cn2[4])  = *reinterpret_cast<const float4*>(&Cc[tn * NS + 4]);
        *reinterpret_cast<float4*>(&Cn2[8])  = *reinterpret_cast<const float4*>(&Cc[tn * NS + 8]);
        *reinterpret_cast<float4*>(&Cn2[12]) = *reinterpret_cast<const float4*>(&Cc[tn * NS + 12]);

        const float dtx = dtv * xv;
        float y = 0.f;
        #pragma unroll
        for (int n = 0; n < NS; ++n) {
            const float dA = __expf(dtv * a[n]);
            h[n] = fmaf(dA, h[n], Bn[n] * dtx);
            y = fmaf(h[n], Cn[n], y);
        }
        yout[t * DI + d] = fmaf(xv, dD, y);

        t = tn; dtv = dtv_n; xv = xv_n;
        #pragma unroll
        for (int n = 0; n < NS; ++n) { Bn[n] = Bn2[n]; Cn[n] = Cn2[n]; }
    }
}

// ---------------- K3: fuse GEMM (y_cat @ Wf^T) * silu(z) ----------------
// grid (NT/64, 6): block = 64 tokens x 32 channels; 4 K-phases of 96.
__global__ __launch_bounds__(256) void k3_fuse(
    const float* __restrict__ yh, const float* __restrict__ yv,
    const float* __restrict__ Wf, const float* __restrict__ sz,
    float* __restrict__ f)
{
    __shared__ float ys[64 * 97];
    const int t0 = blockIdx.x * 64;
    const int lane = threadIdx.x & 63;
    const int wv = __builtin_amdgcn_readfirstlane(threadIdx.x >> 6);
    const int t = t0 + lane;
    const int c0 = blockIdx.y * 32 + wv * 8;

    float acc[8] = {0.f,0.f,0.f,0.f,0.f,0.f,0.f,0.f};

    #pragma unroll
    for (int ph = 0; ph < 4; ++ph) {
        const float* __restrict__ src = (ph < 2) ? yh : yv;
        const int k0 = (ph & 1) * 96;
        __syncthreads();
        for (int idx = threadIdx.x; idx < 64 * 96; idx += 256) {
            const int tt = idx / 96, k = idx - tt * 96;
            ys[tt * 97 + k] = src[(t0 + tt) * DI + k0 + k];
        }
        __syncthreads();
        const int kw = (ph >> 1) * 192 + k0;   // column offset in Wf row (384 wide)
        for (int k = 0; k < 96; k += 4) {
            const float x0 = ys[lane * 97 + k + 0];
            const float x1 = ys[lane * 97 + k + 1];
            const float x2 = ys[lane * 97 + k + 2];
            const float x3 = ys[lane * 97 + k + 3];
            #pragma unroll
            for (int j = 0; j < 8; ++j) {
                const float4 w4 = *reinterpret_cast<const float4*>(&Wf[(c0 + j) * 384 + kw + k]);
                acc[j] = fmaf(x0, w4.x, acc[j]);
                acc[j] = fmaf(x1, w4.y, acc[j]);
                acc[j] = fmaf(x2, w4.z, acc[j]);
                acc[j] = fmaf(x3, w4.w, acc[j]);
            }
        }
    }
    // epilogue: * silu(z) (sz already holds silu(z)), store
    const float4 sa = *reinterpret_cast<const float4*>(&sz[t * DI + c0 + 0]);
    const float4 sb = *reinterpret_cast<const float4*>(&sz[t * DI + c0 + 4]);
    acc[0] *= sa.x; acc[1] *= sa.y; acc[2] *= sa.z; acc[3] *= sa.w;
    acc[4] *= sb.x; acc[5] *= sb.y; acc[6] *= sb.z; acc[7] *= sb.w;
    *reinterpret_cast<float4*>(&f[t * DI + c0 + 0]) = *reinterpret_cast<float4*>(&acc[0]);
    *reinterpret_cast<float4*>(&f[t * DI + c0 + 4]) = *reinterpret_cast<float4*>(&acc[4]);
}

// ---------------- K4: output GEMM ----------------
// grid (NT/64, 3): block = 64 tokens x 32 channels; 2 K-phases of 96.
__global__ __launch_bounds__(256) void k4_out(
    const float* __restrict__ f, const float* __restrict__ Wout,
    float* __restrict__ out)
{
    __shared__ float fs[64 * 97];
    const int t0 = blockIdx.x * 64;
    const int lane = threadIdx.x & 63;
    const int wv = __builtin_amdgcn_readfirstlane(threadIdx.x >> 6);
    const int t = t0 + lane;
    const int c0 = blockIdx.y * 32 + wv * 8;

    float acc[8] = {0.f,0.f,0.f,0.f,0.f,0.f,0.f,0.f};

    #pragma unroll
    for (int ph = 0; ph < 2; ++ph) {
        const int k0 = ph * 96;
        __syncthreads();
        for (int idx = threadIdx.x; idx < 64 * 96; idx += 256) {
            const int tt = idx / 96, k = idx - tt * 96;
            fs[tt * 97 + k] = f[(t0 + tt) * DI + k0 + k];
        }
        __syncthreads();
        for (int k = 0; k < 96; k += 4) {
            const float x0 = fs[lane * 97 + k + 0];
            const float x1 = fs[lane * 97 + k + 1];
            const float x2 = fs[lane * 97 + k + 2];
            const float x3 = fs[lane * 97 + k + 3];
            #pragma unroll
            for (int j = 0; j < 8; ++j) {
                const float4 w4 = *reinterpret_cast<const float4*>(&Wout[(c0 + j) * DI + k0 + k]);
                acc[j] = fmaf(x0, w4.x, acc[j]);
                acc[j] = fmaf(x1, w4.y, acc[j]);
                acc[j] = fmaf(x2, w4.z, acc[j]);
                acc[j] = fmaf(x3, w4.w, acc[j]);
            }
        }
    }
    *reinterpret_cast<float4*>(&out[t * 96 + c0 + 0]) = *reinterpret_cast<float4*>(&acc[0]);
    *reinterpret_cast<float4*>(&out[t * 96 + c0 + 4]) = *reinterpret_cast<float4*>(&acc[4]);
}

extern "C" void kernel_launch(void* const* d_in, const int* in_sizes, int n_in,
                              void* d_out, int out_size, void* d_ws, size_t ws_size,
                              hipStream_t stream)
{
    const float* x     = (const float*)d_in[0];
    const float* Win   = (const float*)d_in[1];
    const float* wconv = (const float*)d_in[2];
    const float* Wf    = (const float*)d_in[3];
    const float* Wout  = (const float*)d_in[4];
    const float* Alog  = (const float*)d_in[5];
    const float* Dvec  = (const float*)d_in[6];
    float* out = (float*)d_out;

    float* ws = (float*)d_ws;
    float* xc = ws;                          // NT*DI
    float* dt = xc + (size_t)NT * DI;        // NT*DI
    float* sz = dt + (size_t)NT * DI;        // NT*DI
    float* Bc = sz + (size_t)NT * DI;        // NT*NS
    float* Cc = Bc + (size_t)NT * NS;        // NT*NS
    float* yh = Cc + (size_t)NT * NS;        // NT*DI
    float* yv = yh + (size_t)NT * DI;        // NT*DI
    float* f  = yv + (size_t)NT * DI;        // NT*DI

    k1_proj<<<dim3(NT / 64, 19), 256, 0, stream>>>(x, Win, wconv, xc, sz, Bc, Cc, dt);
    k2_scan<<<2 * NSEQ, 192, 0, stream>>>(xc, dt, Bc, Cc, Alog, Dvec, yh, yv);
    k3_fuse<<<dim3(NT / 64, 6), 256, 0, stream>>>(yh, yv, Wf, sz, f);
    k4_out<<<dim3(NT / 64, 3), 256, 0, stream>>>(f, Wout, out);
}

// Round 3
// 160.578 us; speedup vs baseline: 2.1158x; 1.0523x over previous
//
#include <hip/hip_runtime.h>
#include <math.h>

#define NT    16384   // tokens = 4*64*64
#define CIN   96
#define DI    192
#define NS    16
#define SEQ   64
#define NSEQ  256     // sequences per direction (B*H == B*W)

__device__ __forceinline__ float silu_f(float v) {
    return v * (1.0f / (1.0f + __expf(-v)));
}

__device__ __forceinline__ float softplus_f(float v) {
    return fmaxf(v, 0.0f) + log1pf(__expf(-fabsf(v)));
}

// ---------------- K1: projection GEMM + activations + split ----------------
// grid (NT/64, 10): block = 512 thr = 8 waves; wave = 64 tok x 8 ch.
__global__ __launch_bounds__(512) void k1_proj(
    const float* __restrict__ x, const float* __restrict__ Win,
    const float* __restrict__ wconv,
    float* __restrict__ xc, float* __restrict__ sz,
    float* __restrict__ Bc, float* __restrict__ Cc, float* __restrict__ dt)
{
    __shared__ float xs[64 * 97];
    const int t0 = blockIdx.x * 64;
    for (int idx = threadIdx.x; idx < 64 * 24; idx += 512) {
        const int tt = idx / 24, kq = (idx - tt * 24) * 4;
        const float4 v = *reinterpret_cast<const float4*>(&x[(t0 + tt) * 96 + kq]);
        xs[tt * 97 + kq + 0] = v.x;
        xs[tt * 97 + kq + 1] = v.y;
        xs[tt * 97 + kq + 2] = v.z;
        xs[tt * 97 + kq + 3] = v.w;
    }
    __syncthreads();
    const int lane = threadIdx.x & 63;
    const int wv = __builtin_amdgcn_readfirstlane(threadIdx.x >> 6);
    const int t = t0 + lane;
    const int c0 = blockIdx.y * 64 + wv * 8;
    if (c0 >= 608) return;

    float acc[8] = {0.f,0.f,0.f,0.f,0.f,0.f,0.f,0.f};
    for (int k = 0; k < 96; k += 4) {
        const float x0 = xs[lane * 97 + k + 0];
        const float x1 = xs[lane * 97 + k + 1];
        const float x2 = xs[lane * 97 + k + 2];
        const float x3 = xs[lane * 97 + k + 3];
        #pragma unroll
        for (int j = 0; j < 8; ++j) {
            const float4 w4 = *reinterpret_cast<const float4*>(&Win[(c0 + j) * 96 + k]);
            acc[j] = fmaf(x0, w4.x, acc[j]);
            acc[j] = fmaf(x1, w4.y, acc[j]);
            acc[j] = fmaf(x2, w4.z, acc[j]);
            acc[j] = fmaf(x3, w4.w, acc[j]);
        }
    }
    if (c0 < DI) {
        #pragma unroll
        for (int j = 0; j < 8; ++j)
            acc[j] = silu_f(acc[j] * wconv[(c0 + j) * 3 + 1]);
        *reinterpret_cast<float4*>(&xc[t * DI + c0 + 0]) = *reinterpret_cast<float4*>(&acc[0]);
        *reinterpret_cast<float4*>(&xc[t * DI + c0 + 4]) = *reinterpret_cast<float4*>(&acc[4]);
    } else if (c0 < 2 * DI) {
        const int c = c0 - DI;
        #pragma unroll
        for (int j = 0; j < 8; ++j) acc[j] = silu_f(acc[j]);
        *reinterpret_cast<float4*>(&sz[t * DI + c + 0]) = *reinterpret_cast<float4*>(&acc[0]);
        *reinterpret_cast<float4*>(&sz[t * DI + c + 4]) = *reinterpret_cast<float4*>(&acc[4]);
    } else if (c0 < 2 * DI + NS) {
        const int c = c0 - 2 * DI;
        *reinterpret_cast<float4*>(&Bc[t * NS + c + 0]) = *reinterpret_cast<float4*>(&acc[0]);
        *reinterpret_cast<float4*>(&Bc[t * NS + c + 4]) = *reinterpret_cast<float4*>(&acc[4]);
    } else if (c0 < 2 * DI + 2 * NS) {
        const int c = c0 - (2 * DI + NS);
        *reinterpret_cast<float4*>(&Cc[t * NS + c + 0]) = *reinterpret_cast<float4*>(&acc[0]);
        *reinterpret_cast<float4*>(&Cc[t * NS + c + 4]) = *reinterpret_cast<float4*>(&acc[4]);
    } else {
        const int c = c0 - (2 * DI + 2 * NS);
        #pragma unroll
        for (int j = 0; j < 8; ++j) acc[j] = softplus_f(acc[j]);
        *reinterpret_cast<float4*>(&dt[t * DI + c + 0]) = *reinterpret_cast<float4*>(&acc[0]);
        *reinterpret_cast<float4*>(&dt[t * DI + c + 4]) = *reinterpret_cast<float4*>(&acc[4]);
    }
}

// ---------------- K2: selective scans (horizontal + vertical) ----------------
__global__ __launch_bounds__(192) void k2_scan(
    const float* __restrict__ xc, const float* __restrict__ dt,
    const float* __restrict__ Bc, const float* __restrict__ Cc,
    const float* __restrict__ Alog, const float* __restrict__ Dvec,
    float* __restrict__ yh, float* __restrict__ yv)
{
    const int d = threadIdx.x;
    const int sid = blockIdx.x;
    const bool vert = sid >= NSEQ;
    const int s0 = vert ? (sid - NSEQ) : sid;

    float a[NS], h[NS];
    #pragma unroll
    for (int n = 0; n < NS; ++n) {
        a[n] = -__expf(Alog[d * NS + n]);
        h[n] = 0.f;
    }
    const float dD = Dvec[d];
    float* __restrict__ yout = vert ? yv : yh;

    const int base = vert ? (((s0 >> 6) << 12) + (s0 & 63)) : (s0 * 64);
    const int stride = vert ? 64 : 1;

    int t = base;
    float dtv = dt[t * DI + d];
    float xv  = xc[t * DI + d];
    float Bn[NS], Cn[NS];
    *reinterpret_cast<float4*>(&Bn[0])  = *reinterpret_cast<const float4*>(&Bc[t * NS + 0]);
    *reinterpret_cast<float4*>(&Bn[4])  = *reinterpret_cast<const float4*>(&Bc[t * NS + 4]);
    *reinterpret_cast<float4*>(&Bn[8])  = *reinterpret_cast<const float4*>(&Bc[t * NS + 8]);
    *reinterpret_cast<float4*>(&Bn[12]) = *reinterpret_cast<const float4*>(&Bc[t * NS + 12]);
    *reinterpret_cast<float4*>(&Cn[0])  = *reinterpret_cast<const float4*>(&Cc[t * NS + 0]);
    *reinterpret_cast<float4*>(&Cn[4])  = *reinterpret_cast<const float4*>(&Cc[t * NS + 4]);
    *reinterpret_cast<float4*>(&Cn[8])  = *reinterpret_cast<const float4*>(&Cc[t * NS + 8]);
    *reinterpret_cast<float4*>(&Cn[12]) = *reinterpret_cast<const float4*>(&Cc[t * NS + 12]);

    #pragma unroll 2
    for (int s = 0; s < SEQ; ++s) {
        const int tn = (s + 1 < SEQ) ? (t + stride) : t;
        const float dtv_n = dt[tn * DI + d];
        const float xv_n  = xc[tn * DI + d];
        float Bn2[NS], Cn2[NS];
        *reinterpret_cast<float4*>(&Bn2[0])  = *reinterpret_cast<const float4*>(&Bc[tn * NS + 0]);
        *reinterpret_cast<float4*>(&Bn2[4])  = *reinterpret_cast<const float4*>(&Bc[tn * NS + 4]);
        *reinterpret_cast<float4*>(&Bn2[8])  = *reinterpret_cast<const float4*>(&Bc[tn * NS + 8]);
        *reinterpret_cast<float4*>(&Bn2[12]) = *reinterpret_cast<const float4*>(&Bc[tn * NS + 12]);
        *reinterpret_cast<float4*>(&Cn2[0])  = *reinterpret_cast<const float4*>(&Cc[tn * NS + 0]);
        *reinterpret_cast<float4*>(&Cn2[4])  = *reinterpret_cast<const float4*>(&Cc[tn * NS + 4]);
        *reinterpret_cast<float4*>(&Cn2[8])  = *reinterpret_cast<const float4*>(&Cc[tn * NS + 8]);
        *reinterpret_cast<float4*>(&Cn2[12]) = *reinterpret_cast<const float4*>(&Cc[tn * NS + 12]);

        const float dtx = dtv * xv;
        float y = 0.f;
        #pragma unroll
        for (int n = 0; n < NS; ++n) {
            const float dA = __expf(dtv * a[n]);
            h[n] = fmaf(dA, h[n], Bn[n] * dtx);
            y = fmaf(h[n], Cn[n], y);
        }
        yout[t * DI + d] = fmaf(xv, dD, y);

        t = tn; dtv = dtv_n; xv = xv_n;
        #pragma unroll
        for (int n = 0; n < NS; ++n) { Bn[n] = Bn2[n]; Cn[n] = Cn2[n]; }
    }
}

// ---------------- K3: fuse GEMM (y_cat @ Wf^T) * silu(z) ----------------
// grid (NT/64, 3): block = 512 thr = 8 waves; wave = 64 tok x 8 ch; 4 K-phases of 96.
__global__ __launch_bounds__(512) void k3_fuse(
    const float* __restrict__ yh, const float* __restrict__ yv,
    const float* __restrict__ Wf, const float* __restrict__ sz,
    float* __restrict__ f)
{
    __shared__ float ys[64 * 97];
    const int t0 = blockIdx.x * 64;
    const int lane = threadIdx.x & 63;
    const int wv = __builtin_amdgcn_readfirstlane(threadIdx.x >> 6);
    const int t = t0 + lane;
    const int c0 = blockIdx.y * 64 + wv * 8;

    float acc[8] = {0.f,0.f,0.f,0.f,0.f,0.f,0.f,0.f};

    #pragma unroll
    for (int ph = 0; ph < 4; ++ph) {
        const float* __restrict__ src = (ph < 2) ? yh : yv;
        const int k0 = (ph & 1) * 96;
        __syncthreads();
        for (int idx = threadIdx.x; idx < 64 * 24; idx += 512) {
            const int tt = idx / 24, kq = (idx - tt * 24) * 4;
            const float4 v = *reinterpret_cast<const float4*>(&src[(t0 + tt) * DI + k0 + kq]);
            ys[tt * 97 + kq + 0] = v.x;
            ys[tt * 97 + kq + 1] = v.y;
            ys[tt * 97 + kq + 2] = v.z;
            ys[tt * 97 + kq + 3] = v.w;
        }
        __syncthreads();
        const int kw = (ph >> 1) * 192 + k0;   // column offset in Wf row (384 wide)
        for (int k = 0; k < 96; k += 4) {
            const float x0 = ys[lane * 97 + k + 0];
            const float x1 = ys[lane * 97 + k + 1];
            const float x2 = ys[lane * 97 + k + 2];
            const float x3 = ys[lane * 97 + k + 3];
            #pragma unroll
            for (int j = 0; j < 8; ++j) {
                const float4 w4 = *reinterpret_cast<const float4*>(&Wf[(c0 + j) * 384 + kw + k]);
                acc[j] = fmaf(x0, w4.x, acc[j]);
                acc[j] = fmaf(x1, w4.y, acc[j]);
                acc[j] = fmaf(x2, w4.z, acc[j]);
                acc[j] = fmaf(x3, w4.w, acc[j]);
            }
        }
    }
    // epilogue: * silu(z) (sz already holds silu(z)), store
    const float4 sa = *reinterpret_cast<const float4*>(&sz[t * DI + c0 + 0]);
    const float4 sb = *reinterpret_cast<const float4*>(&sz[t * DI + c0 + 4]);
    acc[0] *= sa.x; acc[1] *= sa.y; acc[2] *= sa.z; acc[3] *= sa.w;
    acc[4] *= sb.x; acc[5] *= sb.y; acc[6] *= sb.z; acc[7] *= sb.w;
    *reinterpret_cast<float4*>(&f[t * DI + c0 + 0]) = *reinterpret_cast<float4*>(&acc[0]);
    *reinterpret_cast<float4*>(&f[t * DI + c0 + 4]) = *reinterpret_cast<float4*>(&acc[4]);
}

// ---------------- K4: output GEMM ----------------
// grid (NT/64, 3): block = 256 thr = 4 waves; wave = 64 tok x 8 ch; 2 K-phases of 96.
__global__ __launch_bounds__(256) void k4_out(
    const float* __restrict__ f, const float* __restrict__ Wout,
    float* __restrict__ out)
{
    __shared__ float fs[64 * 97];
    const int t0 = blockIdx.x * 64;
    const int lane = threadIdx.x & 63;
    const int wv = __builtin_amdgcn_readfirstlane(threadIdx.x >> 6);
    const int t = t0 + lane;
    const int c0 = blockIdx.y * 32 + wv * 8;

    float acc[8] = {0.f,0.f,0.f,0.f,0.f,0.f,0.f,0.f};

    #pragma unroll
    for (int ph = 0; ph < 2; ++ph) {
        const int k0 = ph * 96;
        __syncthreads();
        for (int idx = threadIdx.x; idx < 64 * 24; idx += 256) {
            const int tt = idx / 24, kq = (idx - tt * 24) * 4;
            const float4 v = *reinterpret_cast<const float4*>(&f[(t0 + tt) * DI + k0 + kq]);
            fs[tt * 97 + kq + 0] = v.x;
            fs[tt * 97 + kq + 1] = v.y;
            fs[tt * 97 + kq + 2] = v.z;
            fs[tt * 97 + kq + 3] = v.w;
        }
        __syncthreads();
        for (int k = 0; k < 96; k += 4) {
            const float x0 = fs[lane * 97 + k + 0];
            const float x1 = fs[lane * 97 + k + 1];
            const float x2 = fs[lane * 97 + k + 2];
            const float x3 = fs[lane * 97 + k + 3];
            #pragma unroll
            for (int j = 0; j < 8; ++j) {
                const float4 w4 = *reinterpret_cast<const float4*>(&Wout[(c0 + j) * DI + k0 + k]);
                acc[j] = fmaf(x0, w4.x, acc[j]);
                acc[j] = fmaf(x1, w4.y, acc[j]);
                acc[j] = fmaf(x2, w4.z, acc[j]);
                acc[j] = fmaf(x3, w4.w, acc[j]);
            }
        }
    }
    *reinterpret_cast<float4*>(&out[t * 96 + c0 + 0]) = *reinterpret_cast<float4*>(&acc[0]);
    *reinterpret_cast<float4*>(&out[t * 96 + c0 + 4]) = *reinterpret_cast<float4*>(&acc[4]);
}

extern "C" void kernel_launch(void* const* d_in, const int* in_sizes, int n_in,
                              void* d_out, int out_size, void* d_ws, size_t ws_size,
                              hipStream_t stream)
{
    const float* x     = (const float*)d_in[0];
    const float* Win   = (const float*)d_in[1];
    const float* wconv = (const float*)d_in[2];
    const float* Wf    = (const float*)d_in[3];
    const float* Wout  = (const float*)d_in[4];
    const float* Alog  = (const float*)d_in[5];
    const float* Dvec  = (const float*)d_in[6];
    float* out = (float*)d_out;

    float* ws = (float*)d_ws;
    float* xc = ws;                          // NT*DI
    float* dt = xc + (size_t)NT * DI;        // NT*DI
    float* sz = dt + (size_t)NT * DI;        // NT*DI
    float* Bc = sz + (size_t)NT * DI;        // NT*NS
    float* Cc = Bc + (size_t)NT * NS;        // NT*NS
    float* yh = Cc + (size_t)NT * NS;        // NT*DI
    float* yv = yh + (size_t)NT * DI;        // NT*DI
    float* f  = yv + (size_t)NT * DI;        // NT*DI

    k1_proj<<<dim3(NT / 64, 10), 512, 0, stream>>>(x, Win, wconv, xc, sz, Bc, Cc, dt);
    k2_scan<<<2 * NSEQ, 192, 0, stream>>>(xc, dt, Bc, Cc, Alog, Dvec, yh, yv);
    k3_fuse<<<dim3(NT / 64, 3), 512, 0, stream>>>(yh, yv, Wf, sz, f);
    k4_out<<<dim3(NT / 64, 3), 256, 0, stream>>>(f, Wout, out);
}

// Round 4
// 154.742 us; speedup vs baseline: 2.1956x; 1.0377x over previous
//
#include <hip/hip_runtime.h>
#include <math.h>

#define NT    16384   // tokens = 4*64*64
#define CIN   96
#define DI    192
#define NS    16
#define SEQ   64
#define NSEQ  256     // sequences per direction (B*H == B*W)

#define TOK   128     // tokens per block (GEMM kernels), 2 per lane
#define KC    48      // K-chunk staged in LDS
#define PAD   49      // LDS row pitch (coprime with 32 -> conflict-free)

__device__ __forceinline__ float silu_f(float v) {
    return v * (1.0f / (1.0f + __expf(-v)));
}

__device__ __forceinline__ float softplus_f(float v) {
    return fmaxf(v, 0.0f) + log1pf(__expf(-fabsf(v)));
}

// ---------------- K1: projection GEMM + activations + split ----------------
// grid (NT/128, 19): block = 256 thr = 4 waves; wave = 8 ch x 128 tok (2/lane).
__global__ __launch_bounds__(256) void k1_proj(
    const float* __restrict__ x, const float* __restrict__ Win,
    const float* __restrict__ wconv,
    float* __restrict__ xc, float* __restrict__ sz,
    float* __restrict__ Bc, float* __restrict__ Cc, float* __restrict__ dt)
{
    __shared__ float xs[TOK * PAD];
    const int t0 = blockIdx.x * TOK;
    const int lane = threadIdx.x & 63;
    const int wv = __builtin_amdgcn_readfirstlane(threadIdx.x >> 6);
    const int c0 = blockIdx.y * 32 + wv * 8;   // 19*32 = 608 exactly, no guard

    float acc[2][8];
    #pragma unroll
    for (int m = 0; m < 2; ++m)
        #pragma unroll
        for (int j = 0; j < 8; ++j) acc[m][j] = 0.f;

    #pragma unroll
    for (int kc = 0; kc < 2; ++kc) {               // K = 96 = 2 x 48
        const int k0 = kc * KC;
        __syncthreads();
        for (int idx = threadIdx.x; idx < TOK * (KC / 4); idx += 256) {
            const int tt = idx / (KC / 4), q = idx - tt * (KC / 4);
            const float4 v = *reinterpret_cast<const float4*>(&x[(t0 + tt) * CIN + k0 + q * 4]);
            float* dsm = &xs[tt * PAD + q * 4];
            dsm[0] = v.x; dsm[1] = v.y; dsm[2] = v.z; dsm[3] = v.w;
        }
        __syncthreads();
        for (int kk = 0; kk < KC; kk += 4) {
            float y0[2][4];
            #pragma unroll
            for (int m = 0; m < 2; ++m)
                #pragma unroll
                for (int i = 0; i < 4; ++i)
                    y0[m][i] = xs[(lane + 64 * m) * PAD + kk + i];
            #pragma unroll
            for (int j = 0; j < 8; ++j) {
                const float4 w4 = *reinterpret_cast<const float4*>(&Win[(c0 + j) * CIN + k0 + kk]);
                #pragma unroll
                for (int m = 0; m < 2; ++m) {
                    acc[m][j] = fmaf(y0[m][0], w4.x, acc[m][j]);
                    acc[m][j] = fmaf(y0[m][1], w4.y, acc[m][j]);
                    acc[m][j] = fmaf(y0[m][2], w4.z, acc[m][j]);
                    acc[m][j] = fmaf(y0[m][3], w4.w, acc[m][j]);
                }
            }
        }
    }

    #pragma unroll
    for (int m = 0; m < 2; ++m) {
        const int t = t0 + lane + 64 * m;
        float* a = acc[m];
        if (c0 < DI) {
            #pragma unroll
            for (int j = 0; j < 8; ++j)
                a[j] = silu_f(a[j] * wconv[(c0 + j) * 3 + 1]);
            *reinterpret_cast<float4*>(&xc[t * DI + c0 + 0]) = *reinterpret_cast<float4*>(&a[0]);
            *reinterpret_cast<float4*>(&xc[t * DI + c0 + 4]) = *reinterpret_cast<float4*>(&a[4]);
        } else if (c0 < 2 * DI) {
            const int c = c0 - DI;
            #pragma unroll
            for (int j = 0; j < 8; ++j) a[j] = silu_f(a[j]);
            *reinterpret_cast<float4*>(&sz[t * DI + c + 0]) = *reinterpret_cast<float4*>(&a[0]);
            *reinterpret_cast<float4*>(&sz[t * DI + c + 4]) = *reinterpret_cast<float4*>(&a[4]);
        } else if (c0 < 2 * DI + NS) {
            const int c = c0 - 2 * DI;
            *reinterpret_cast<float4*>(&Bc[t * NS + c + 0]) = *reinterpret_cast<float4*>(&a[0]);
            *reinterpret_cast<float4*>(&Bc[t * NS + c + 4]) = *reinterpret_cast<float4*>(&a[4]);
        } else if (c0 < 2 * DI + 2 * NS) {
            const int c = c0 - (2 * DI + NS);
            *reinterpret_cast<float4*>(&Cc[t * NS + c + 0]) = *reinterpret_cast<float4*>(&a[0]);
            *reinterpret_cast<float4*>(&Cc[t * NS + c + 4]) = *reinterpret_cast<float4*>(&a[4]);
        } else {
            const int c = c0 - (2 * DI + 2 * NS);
            #pragma unroll
            for (int j = 0; j < 8; ++j) a[j] = softplus_f(a[j]);
            *reinterpret_cast<float4*>(&dt[t * DI + c + 0]) = *reinterpret_cast<float4*>(&a[0]);
            *reinterpret_cast<float4*>(&dt[t * DI + c + 4]) = *reinterpret_cast<float4*>(&a[4]);
        }
    }
}

// ---------------- K2: selective scans (horizontal + vertical) ----------------
__global__ __launch_bounds__(192) void k2_scan(
    const float* __restrict__ xc, const float* __restrict__ dt,
    const float* __restrict__ Bc, const float* __restrict__ Cc,
    const float* __restrict__ Alog, const float* __restrict__ Dvec,
    float* __restrict__ yh, float* __restrict__ yv)
{
    const int d = threadIdx.x;
    const int sid = blockIdx.x;
    const bool vert = sid >= NSEQ;
    const int s0 = vert ? (sid - NSEQ) : sid;

    float a[NS], h[NS];
    #pragma unroll
    for (int n = 0; n < NS; ++n) {
        a[n] = -__expf(Alog[d * NS + n]);
        h[n] = 0.f;
    }
    const float dD = Dvec[d];
    float* __restrict__ yout = vert ? yv : yh;

    const int base = vert ? (((s0 >> 6) << 12) + (s0 & 63)) : (s0 * 64);
    const int stride = vert ? 64 : 1;

    int t = base;
    float dtv = dt[t * DI + d];
    float xv  = xc[t * DI + d];
    float Bn[NS], Cn[NS];
    *reinterpret_cast<float4*>(&Bn[0])  = *reinterpret_cast<const float4*>(&Bc[t * NS + 0]);
    *reinterpret_cast<float4*>(&Bn[4])  = *reinterpret_cast<const float4*>(&Bc[t * NS + 4]);
    *reinterpret_cast<float4*>(&Bn[8])  = *reinterpret_cast<const float4*>(&Bc[t * NS + 8]);
    *reinterpret_cast<float4*>(&Bn[12]) = *reinterpret_cast<const float4*>(&Bc[t * NS + 12]);
    *reinterpret_cast<float4*>(&Cn[0])  = *reinterpret_cast<const float4*>(&Cc[t * NS + 0]);
    *reinterpret_cast<float4*>(&Cn[4])  = *reinterpret_cast<const float4*>(&Cc[t * NS + 4]);
    *reinterpret_cast<float4*>(&Cn[8])  = *reinterpret_cast<const float4*>(&Cc[t * NS + 8]);
    *reinterpret_cast<float4*>(&Cn[12]) = *reinterpret_cast<const float4*>(&Cc[t * NS + 12]);

    #pragma unroll 2
    for (int s = 0; s < SEQ; ++s) {
        const int tn = (s + 1 < SEQ) ? (t + stride) : t;
        const float dtv_n = dt[tn * DI + d];
        const float xv_n  = xc[tn * DI + d];
        float Bn2[NS], Cn2[NS];
        *reinterpret_cast<float4*>(&Bn2[0])  = *reinterpret_cast<const float4*>(&Bc[tn * NS + 0]);
        *reinterpret_cast<float4*>(&Bn2[4])  = *reinterpret_cast<const float4*>(&Bc[tn * NS + 4]);
        *reinterpret_cast<float4*>(&Bn2[8])  = *reinterpret_cast<const float4*>(&Bc[tn * NS + 8]);
        *reinterpret_cast<float4*>(&Bn2[12]) = *reinterpret_cast<const float4*>(&Bc[tn * NS + 12]);
        *reinterpret_cast<float4*>(&Cn2[0])  = *reinterpret_cast<const float4*>(&Cc[tn * NS + 0]);
        *reinterpret_cast<float4*>(&Cn2[4])  = *reinterpret_cast<const float4*>(&Cc[tn * NS + 4]);
        *reinterpret_cast<float4*>(&Cn2[8])  = *reinterpret_cast<const float4*>(&Cc[tn * NS + 8]);
        *reinterpret_cast<float4*>(&Cn2[12]) = *reinterpret_cast<const float4*>(&Cc[tn * NS + 12]);

        const float dtx = dtv * xv;
        float y = 0.f;
        #pragma unroll
        for (int n = 0; n < NS; ++n) {
            const float dA = __expf(dtv * a[n]);
            h[n] = fmaf(dA, h[n], Bn[n] * dtx);
            y = fmaf(h[n], Cn[n], y);
        }
        yout[t * DI + d] = fmaf(xv, dD, y);

        t = tn; dtv = dtv_n; xv = xv_n;
        #pragma unroll
        for (int n = 0; n < NS; ++n) { Bn[n] = Bn2[n]; Cn[n] = Cn2[n]; }
    }
}

// ---------------- K3: fuse GEMM (y_cat @ Wf^T) * silu(z) ----------------
// grid (NT/128, 6): block = 256 thr = 4 waves; wave = 8 ch x 128 tok (2/lane).
// K = 384 = 8 chunks of 48 (chunks 0-3 from yh, 4-7 from yv).
__global__ __launch_bounds__(256) void k3_fuse(
    const float* __restrict__ yh, const float* __restrict__ yv,
    const float* __restrict__ Wf, const float* __restrict__ sz,
    float* __restrict__ f)
{
    __shared__ float ys[TOK * PAD];
    const int t0 = blockIdx.x * TOK;
    const int lane = threadIdx.x & 63;
    const int wv = __builtin_amdgcn_readfirstlane(threadIdx.x >> 6);
    const int c0 = blockIdx.y * 32 + wv * 8;

    float acc[2][8];
    #pragma unroll
    for (int m = 0; m < 2; ++m)
        #pragma unroll
        for (int j = 0; j < 8; ++j) acc[m][j] = 0.f;

    #pragma unroll
    for (int kc = 0; kc < 8; ++kc) {
        const float* __restrict__ src = (kc < 4) ? yh : yv;
        const int koff = (kc & 3) * KC;            // offset within src row
        const int kw = kc * KC;                    // offset within Wf row (384)
        __syncthreads();
        for (int idx = threadIdx.x; idx < TOK * (KC / 4); idx += 256) {
            const int tt = idx / (KC / 4), q = idx - tt * (KC / 4);
            const float4 v = *reinterpret_cast<const float4*>(&src[(t0 + tt) * DI + koff + q * 4]);
            float* dsm = &ys[tt * PAD + q * 4];
            dsm[0] = v.x; dsm[1] = v.y; dsm[2] = v.z; dsm[3] = v.w;
        }
        __syncthreads();
        for (int kk = 0; kk < KC; kk += 4) {
            float y0[2][4];
            #pragma unroll
            for (int m = 0; m < 2; ++m)
                #pragma unroll
                for (int i = 0; i < 4; ++i)
                    y0[m][i] = ys[(lane + 64 * m) * PAD + kk + i];
            #pragma unroll
            for (int j = 0; j < 8; ++j) {
                const float4 w4 = *reinterpret_cast<const float4*>(&Wf[(c0 + j) * 384 + kw + kk]);
                #pragma unroll
                for (int m = 0; m < 2; ++m) {
                    acc[m][j] = fmaf(y0[m][0], w4.x, acc[m][j]);
                    acc[m][j] = fmaf(y0[m][1], w4.y, acc[m][j]);
                    acc[m][j] = fmaf(y0[m][2], w4.z, acc[m][j]);
                    acc[m][j] = fmaf(y0[m][3], w4.w, acc[m][j]);
                }
            }
        }
    }

    #pragma unroll
    for (int m = 0; m < 2; ++m) {
        const int t = t0 + lane + 64 * m;
        float* a = acc[m];
        const float4 sa = *reinterpret_cast<const float4*>(&sz[t * DI + c0 + 0]);
        const float4 sb = *reinterpret_cast<const float4*>(&sz[t * DI + c0 + 4]);
        a[0] *= sa.x; a[1] *= sa.y; a[2] *= sa.z; a[3] *= sa.w;
        a[4] *= sb.x; a[5] *= sb.y; a[6] *= sb.z; a[7] *= sb.w;
        *reinterpret_cast<float4*>(&f[t * DI + c0 + 0]) = *reinterpret_cast<float4*>(&a[0]);
        *reinterpret_cast<float4*>(&f[t * DI + c0 + 4]) = *reinterpret_cast<float4*>(&a[4]);
    }
}

// ---------------- K4: output GEMM ----------------
// grid (NT/64, 3): block = 256 thr = 4 waves; wave = 64 tok x 8 ch; 2 K-phases of 96.
__global__ __launch_bounds__(256) void k4_out(
    const float* __restrict__ f, const float* __restrict__ Wout,
    float* __restrict__ out)
{
    __shared__ float fs[64 * 97];
    const int t0 = blockIdx.x * 64;
    const int lane = threadIdx.x & 63;
    const int wv = __builtin_amdgcn_readfirstlane(threadIdx.x >> 6);
    const int t = t0 + lane;
    const int c0 = blockIdx.y * 32 + wv * 8;

    float acc[8] = {0.f,0.f,0.f,0.f,0.f,0.f,0.f,0.f};

    #pragma unroll
    for (int ph = 0; ph < 2; ++ph) {
        const int k0 = ph * 96;
        __syncthreads();
        for (int idx = threadIdx.x; idx < 64 * 24; idx += 256) {
            const int tt = idx / 24, kq = (idx - tt * 24) * 4;
            const float4 v = *reinterpret_cast<const float4*>(&f[(t0 + tt) * DI + k0 + kq]);
            fs[tt * 97 + kq + 0] = v.x;
            fs[tt * 97 + kq + 1] = v.y;
            fs[tt * 97 + kq + 2] = v.z;
            fs[tt * 97 + kq + 3] = v.w;
        }
        __syncthreads();
        for (int k = 0; k < 96; k += 4) {
            const float x0 = fs[lane * 97 + k + 0];
            const float x1 = fs[lane * 97 + k + 1];
            const float x2 = fs[lane * 97 + k + 2];
            const float x3 = fs[lane * 97 + k + 3];
            #pragma unroll
            for (int j = 0; j < 8; ++j) {
                const float4 w4 = *reinterpret_cast<const float4*>(&Wout[(c0 + j) * DI + k0 + k]);
                acc[j] = fmaf(x0, w4.x, acc[j]);
                acc[j] = fmaf(x1, w4.y, acc[j]);
                acc[j] = fmaf(x2, w4.z, acc[j]);
                acc[j] = fmaf(x3, w4.w, acc[j]);
            }
        }
    }
    *reinterpret_cast<float4*>(&out[t * 96 + c0 + 0]) = *reinterpret_cast<float4*>(&acc[0]);
    *reinterpret_cast<float4*>(&out[t * 96 + c0 + 4]) = *reinterpret_cast<float4*>(&acc[4]);
}

extern "C" void kernel_launch(void* const* d_in, const int* in_sizes, int n_in,
                              void* d_out, int out_size, void* d_ws, size_t ws_size,
                              hipStream_t stream)
{
    const float* x     = (const float*)d_in[0];
    const float* Win   = (const float*)d_in[1];
    const float* wconv = (const float*)d_in[2];
    const float* Wf    = (const float*)d_in[3];
    const float* Wout  = (const float*)d_in[4];
    const float* Alog  = (const float*)d_in[5];
    const float* Dvec  = (const float*)d_in[6];
    float* out = (float*)d_out;

    float* ws = (float*)d_ws;
    float* xc = ws;                          // NT*DI
    float* dt = xc + (size_t)NT * DI;        // NT*DI
    float* sz = dt + (size_t)NT * DI;        // NT*DI
    float* Bc = sz + (size_t)NT * DI;        // NT*NS
    float* Cc = Bc + (size_t)NT * NS;        // NT*NS
    float* yh = Cc + (size_t)NT * NS;        // NT*DI
    float* yv = yh + (size_t)NT * DI;        // NT*DI
    float* f  = yv + (size_t)NT * DI;        // NT*DI

    k1_proj<<<dim3(NT / TOK, 19), 256, 0, stream>>>(x, Win, wconv, xc, sz, Bc, Cc, dt);
    k2_scan<<<2 * NSEQ, 192, 0, stream>>>(xc, dt, Bc, Cc, Alog, Dvec, yh, yv);
    k3_fuse<<<dim3(NT / TOK, 6), 256, 0, stream>>>(yh, yv, Wf, sz, f);
    k4_out<<<dim3(NT / 64, 3), 256, 0, stream>>>(f, Wout, out);
}